// Round 6
// baseline (23.591 us; speedup 1.0000x reference)
//
#include <hip/hip_runtime.h>
#include <hip/hip_fp16.h>
#include <math.h>

// dist[b,n] = sum_d softplus(fw[d]) * |q[b,d] - X[n,d]|
//           = sum_d |wq[b,d] - wx[n,d]|,  wq = w*q, wx = w*X, w = softplus(fw) > 0
//
// Round 6: round-5 kernel with ONE change — BCHUNK 16 -> 8, doubling the grid
// (392 -> 784 blocks, 6.1 -> 12.25 waves/CU). Rounds 2/4/5 all plateaued at
// ~22 us with different inner loops; common factor was wave starvation.
// fp16 packed inner loop (3 instr / 2 elems), per-wave barrier-free LDS
// transpose staging, broadcast ds_read_b128 for q, XCD-swizzled grid.

constexpr int D = 64;
constexpr int BCHUNK = 8;    // b-values per block (8 chunks over B=64)
constexpr int NT = 256;      // 4 waves
constexpr int ROWS = 512;    // X rows per block (2 per thread)
constexpr int PADH = 72;     // LDS halfs per staged row (144 B stride)

__global__ __launch_bounds__(NT, 4)
void fdist_kernel(const float* __restrict__ q,
                  const float* __restrict__ X,
                  const float* __restrict__ fw,
                  float* __restrict__ out, int N) {
    __shared__ float ws[D];
    __shared__ __align__(16) __half qs[BCHUNK][D];       // 1 KB
    __shared__ __align__(16) __half xbuf[4][64 * PADH];  // 4 x 9216 B

    const int t = threadIdx.x;
    const int w = t >> 6, l = t & 63;

    // bijective XCD swizzle (nwg % 8 == 0), x-outer / y-inner decode:
    // consecutive wg on one XCD share the same X slice across 8 b-chunks.
    const int nwg = gridDim.x, cpx = nwg >> 3;
    const int wg = (blockIdx.x & 7) * cpx + (blockIdx.x >> 3);
    const int nbase = (wg >> 3) * ROWS;
    const int bbase = (wg & 7) * BCHUNK;

    // softplus(fw) -> ws
    if (t < D) {
        float x = fw[t];
        ws[t] = fmaxf(x, 0.f) + log1pf(expf(-fabsf(x)));
    }
    __syncthreads();

    // ---- q tile: scaled + packed to fp16, [8][64] halfs (row = 128 B) ----
    const float2* q2 = reinterpret_cast<const float2*>(q);
    if (t < BCHUNK * 32) {
        const float2 v = q2[(size_t)bbase * 32 + t];
        const int d = (t & 31) * 2;
        *reinterpret_cast<__half2*>(&qs[t >> 5][d]) =
            __floats2half2_rn(v.x * ws[d], v.y * ws[d + 1]);
    }

    // per-lane column weights for X staging
    const int col = l & 15, rsub = l >> 4;
    const float4 wv = {ws[col * 4], ws[col * 4 + 1], ws[col * 4 + 2], ws[col * 4 + 3]};

    // ---- X: per-wave barrier-free transpose staging, 2 parts of 64 rows ----
    __half* wb = xbuf[w];
    const float4* Xv = reinterpret_cast<const float4*>(X);
    __half2 xr[2][32];                             // 2 rows x 64 halfs in VGPRs

    union H4 { float4 f; __half2 h[4]; };
    union H2 { float2 f; __half2 h[2]; };

#pragma unroll
    for (int p = 0; p < 2; ++p) {
#pragma unroll
        for (int j = 0; j < 16; ++j) {
            const int r = j * 4 + rsub;            // 0..63
            int grow = nbase + w * 128 + p * 64 + r;
            grow = grow < N ? grow : N - 1;
            const float4 v = Xv[(size_t)grow * 16 + col];   // coalesced 1 KB/instr
            H2 u;
            u.h[0] = __floats2half2_rn(v.x * wv.x, v.y * wv.y);
            u.h[1] = __floats2half2_rn(v.z * wv.z, v.w * wv.w);
            *reinterpret_cast<float2*>(&wb[r * PADH + col * 4]) = u.f;
        }
        asm volatile("s_waitcnt lgkmcnt(0)" ::: "memory");  // wave-local RAW
#pragma unroll
        for (int i = 0; i < 8; ++i) {
            H4 u;
            u.f = *reinterpret_cast<const float4*>(&wb[l * PADH + i * 8]);
#pragma unroll
            for (int k = 0; k < 4; ++k) xr[p][i * 4 + k] = u.h[k];
        }
        asm volatile("s_waitcnt lgkmcnt(0)" ::: "memory");  // drain before restage
    }
    __syncthreads();   // qs visible to all waves

    const int nA = nbase + w * 128 + l;
    const int nB = nA + 64;
    const float4* qs4 = reinterpret_cast<const float4*>(qs);  // [8][8]

    // ---- main loop: 8 b-rows; q via broadcast ds_read_b128, X in VGPRs ----
#pragma unroll 2
    for (int bi = 0; bi < BCHUNK; ++bi) {
        const __half2 z = __float2half2_rn(0.f);
        __half2 a0 = z, a1 = z, b0 = z, b1 = z;
#pragma unroll
        for (int i = 0; i < 8; ++i) {
            H4 qv;
            qv.f = qs4[bi * 8 + i];                // uniform -> broadcast
#pragma unroll
            for (int k = 0; k < 4; ++k) {
                const __half2 dA = __habs2(__hsub2(qv.h[k], xr[0][i * 4 + k]));
                const __half2 dB = __habs2(__hsub2(qv.h[k], xr[1][i * 4 + k]));
                if (k & 1) { a1 = __hadd2(a1, dA); b1 = __hadd2(b1, dB); }
                else       { a0 = __hadd2(a0, dA); b0 = __hadd2(b0, dB); }
            }
        }
        const __half2 sa = __hadd2(a0, a1), sb = __hadd2(b0, b1);
        float* orow = out + (size_t)(bbase + bi) * N;
        if (nA < N) orow[nA] = __low2float(sa) + __high2float(sa);
        if (nB < N) orow[nB] = __low2float(sb) + __high2float(sb);
    }
}

extern "C" void kernel_launch(void* const* d_in, const int* in_sizes, int n_in,
                              void* d_out, int out_size, void* d_ws, size_t ws_size,
                              hipStream_t stream) {
    const float* q  = (const float*)d_in[0];
    const float* X  = (const float*)d_in[1];
    const float* fw = (const float*)d_in[2];
    float* out = (float*)d_out;

    const int B = in_sizes[0] / D;  // 64
    const int N = in_sizes[1] / D;  // 50000

    const int nxblk = (N + ROWS - 1) / ROWS;      // 98
    const int nwg = nxblk * (B / BCHUNK);         // 784 (divisible by 8)
    fdist_kernel<<<dim3(nwg), dim3(NT), 0, stream>>>(q, X, fw, out, N);
}